// Round 16
// baseline (241.300 us; speedup 1.0000x reference)
//
#include <hip/hip_runtime.h>
#include <stdint.h>

typedef unsigned short ushort_t;
typedef __attribute__((ext_vector_type(8))) short short8;
typedef __attribute__((ext_vector_type(4))) float floatx4;
typedef __attribute__((ext_vector_type(4))) unsigned short ushortx4;
typedef __attribute__((ext_vector_type(8))) unsigned short ushortx8;

#define B_   16
#define CIN  128
#define CH   256
#define HW   96
#define HP   98

// ws layout (bytes)
#define XPAD_ELEMS (B_*HP*HP*CIN)            // bf16 elems
#define HPAD_ELEMS (B_*HP*HP*CH)             // bf16 elems
#define XPAD_OFF 0
#define HPAD_OFF (XPAD_ELEMS*2)
#define W1T_OFF  (HPAD_OFF + HPAD_ELEMS*2)
#define W2T_OFF  (W1T_OFF + 256*1152*2)

__device__ __forceinline__ ushort_t f2bf(float f){
  uint32_t u = __float_as_uint(f);
  u += 0x7FFF + ((u >> 16) & 1);   // RNE
  return (ushort_t)(u >> 16);
}
__device__ __forceinline__ float bf2f(ushort_t h){
  return __uint_as_float(((uint32_t)h) << 16);
}
__device__ __forceinline__ void async_ld16(void* lds, const void* g){
  __builtin_amdgcn_global_load_lds(
      (const __attribute__((address_space(1))) void*)g,
      (__attribute__((address_space(3))) void*)lds, 16, 0, 0);
}

// Zero one border word of a padded NHWC tensor. C2 = channels/2 (u32 words/cell).
__device__ __forceinline__ void zb(uint32_t* base, int C2, int tid){
  int perimg = 388*C2;
  int b = tid / perimg; int r = tid % perimg;
  int cell = r / C2;    int cu = r % C2;
  int y, x;
  if      (cell < 98)  { y = 0;            x = cell;       }
  else if (cell < 196) { y = 97;           x = cell - 98;  }
  else if (cell < 292) { y = cell - 195;   x = 0;          }
  else                 { y = cell - 291;   x = 97;         }
  base[((b*HP + y)*HP + x)*C2 + cu] = 0u;
}

// Fused prep: blocks [0,1152) = transform_x (NCHW fp32 -> padded NHWC bf16,
// 4 y-rows per block, full 256B-line stores); blocks [1152,6978) = border
// zeroing + w transforms.
__global__ __launch_bounds__(256) void prep_all(const float* __restrict__ x,
                                                const float* __restrict__ w1,
                                                const float* __restrict__ w2,
                                                uint32_t* __restrict__ xpadw,
                                                uint32_t* __restrict__ hpadw,
                                                ushort_t* __restrict__ w1t,
                                                float* __restrict__ w2t,
                                                ushort_t* __restrict__ xpad){
  __shared__ float lds[128][33];
  int bidx = blockIdx.x;
  int t = threadIdx.x;
  if (bidx < 1152){
    int xt = bidx % 3; int yt = (bidx/3) % 24; int b = bidx/72;
    int x0 = xt*32, y0 = yt*4;
    for (int yy=0; yy<4; ++yy){
      int y = y0 + yy;
      #pragma unroll
      for (int rep=0; rep<16; ++rep){
        int idx = rep*256 + t;
        int ci = idx >> 5, xj = idx & 31;
        lds[ci][xj] = x[((b*CIN + ci)*HW + y)*HW + x0 + xj];
      }
      __syncthreads();
      int px = t & 31, oc = t >> 5;      // oc = 16-channel group (0..7)
      ushort_t* dst = &xpad[((b*HP + y+1)*HP + x0+px+1)*CIN + oc*16];
      ushortx8 v0, v1;
      #pragma unroll
      for (int k=0;k<8;k++) v0[k] = f2bf(lds[oc*16+k][px]);
      #pragma unroll
      for (int k=0;k<8;k++) v1[k] = f2bf(lds[oc*16+8+k][px]);
      *(ushortx8*)dst = v0;
      *(ushortx8*)(dst+8) = v1;
      __syncthreads();
    }
  } else {
    int tid = (bidx - 1152)*256 + t;
    const int NZX = B_*388*64;
    const int NZH = B_*388*128;
    const int NW1 = 256*1152;
    if (tid < NZX){
      zb(xpadw, 64, tid);
    } else if (tid < NZX + NZH){
      zb(hpadw, 128, tid - NZX);
    } else if (tid < NZX + NZH + NW1){
      int r = tid - (NZX + NZH);
      int o = r / 1152, k = r - o*1152;
      int tap = k >> 7, c = k & 127;
      w1t[r] = f2bf(w1[(o*CIN + c)*9 + tap]);
    } else {
      int r = tid - (NZX + NZH + NW1);   // < 4608
      int ch = r & 1, c = (r >> 1) & 255, tap = r >> 9;
      w2t[r] = w2[(ch*CH + c)*9 + tap];
    }
  }
}

// ---------------------------------------------------------------------------
// conv1 v12: split the two operands across pipes. A (weights) stays in LDS
// (2-buf x 16KB = 32 KB, T2 both-sides swizzle, gload_lds staged 1 ahead);
// B (pixels) is read DIRECTLY from xpad as per-lane global_load_dwordx4
// (L1/L2-resident: per-tile unique B = 16KB, w-dup x2 absorbed by L1).
// LDS pipe drops to A-only (~770 cyc/tile/CU << MFMA 1863); vmem pipe
// (idle before: HBM 13%) takes B. LDS 32 KB + launch_bounds(256,3) ->
// 3 blocks/CU co-resident: TLP fills the barrier drains that defeated all
// scheduling fixes (m114 mechanism). Geometry = 128x128 tile, BK=64, 18
// K-tiles, 4 waves 2Mx2N (wave 64x64, acc[4][4]), 4-phase/8-barrier
// skeleton, T5 setprio, XCD swizzle (2304 % 8 == 0).
// vmcnt ordering: P0 issues B-k0 then A-stage j0,j1 -> compiler's B-wait
// (vmcnt(2)) leaves A-stage in flight; P2's B-k1 wait drains A naturally;
// entry vmcnt(0) is free insurance. Per-element accumulation order
// identical to r12 (kt asc, k0 then k1, same nf/mf order) -> output
// bit-identical (absmax must stay exactly 0.015625).
// ---------------------------------------------------------------------------
#define C1_TILE(KT, SA) { \
  asm volatile("s_waitcnt vmcnt(0)" ::: "memory"); \
  __builtin_amdgcn_s_barrier(); \
  __builtin_amdgcn_sched_barrier(0); \
  const int kt_ = (KT); \
  const ushort_t* Ab = &Alds[(kt_ & 1) * 8192]; \
  const int tap_ = kt_ >> 1; \
  const int dy_ = tap_/3; const int dx_ = tap_ - dy_*3; \
  const int bd_ = (dy_*HP + dx_)*CIN + (kt_&1)*64; \
  short8 a0[4], a1[4], b0[2], b1[2], b2v[2], b3[2]; \
  /* ---- P0: B-k0 global loads; A-k0 ds_reads; stage A(kt+1) j0,j1 ---- */ \
  b0[0] = *(const short8*)&xpad[bgoff[0] + bd_]; \
  b0[1] = *(const short8*)&xpad[bgoff[1] + bd_]; \
  b1[0] = *(const short8*)&xpad[bgoff[2] + bd_]; \
  b1[1] = *(const short8*)&xpad[bgoff[3] + bd_]; \
  _Pragma("unroll") \
  for (int mf=0; mf<4; ++mf) a0[mf] = *(const short8*)&Ab[abase_r + mf*1024 + koff0]; \
  if (SA) { \
    const int ka_ = kt_ + 1; const int ab_ = (ka_ & 1) * 8192; \
    async_ld16(&Alds[ab_ +    0 + adst], &w1t[asrc +       0 + ka_*64]); \
    async_ld16(&Alds[ab_ + 2048 + adst], &w1t[asrc +   36864 + ka_*64]); \
  } \
  __builtin_amdgcn_s_barrier(); \
  asm volatile("s_waitcnt lgkmcnt(0)" ::: "memory"); \
  __builtin_amdgcn_sched_barrier(0); \
  __builtin_amdgcn_s_setprio(1); \
  _Pragma("unroll") \
  for (int mf=0; mf<4; ++mf) \
    _Pragma("unroll") \
    for (int nf=0; nf<2; ++nf) \
      acc[mf][nf] = __builtin_amdgcn_mfma_f32_16x16x32_bf16(a0[mf], b0[nf], acc[mf][nf], 0,0,0); \
  __builtin_amdgcn_s_setprio(0); \
  __builtin_amdgcn_s_barrier(); \
  __builtin_amdgcn_sched_barrier(0); \
  /* ---- P1: stage A(kt+1) j2,j3; MFMA a0 x b1 ---- */ \
  if (SA) { \
    const int ka_ = kt_ + 1; const int ab_ = (ka_ & 1) * 8192; \
    async_ld16(&Alds[ab_ + 4096 + adst], &w1t[asrc + 2*36864 + ka_*64]); \
    async_ld16(&Alds[ab_ + 6144 + adst], &w1t[asrc + 3*36864 + ka_*64]); \
  } \
  __builtin_amdgcn_s_barrier(); \
  asm volatile("s_waitcnt lgkmcnt(0)" ::: "memory"); \
  __builtin_amdgcn_sched_barrier(0); \
  __builtin_amdgcn_s_setprio(1); \
  _Pragma("unroll") \
  for (int mf=0; mf<4; ++mf) \
    _Pragma("unroll") \
    for (int nf=0; nf<2; ++nf) \
      acc[mf][nf+2] = __builtin_amdgcn_mfma_f32_16x16x32_bf16(a0[mf], b1[nf], acc[mf][nf+2], 0,0,0); \
  __builtin_amdgcn_s_setprio(0); \
  __builtin_amdgcn_s_barrier(); \
  __builtin_amdgcn_sched_barrier(0); \
  /* ---- P2: B-k1 global loads; A-k1 ds_reads; MFMA a1 x b2 ---- */ \
  b2v[0] = *(const short8*)&xpad[bgoff[0] + bd_ + 32]; \
  b2v[1] = *(const short8*)&xpad[bgoff[1] + bd_ + 32]; \
  b3[0]  = *(const short8*)&xpad[bgoff[2] + bd_ + 32]; \
  b3[1]  = *(const short8*)&xpad[bgoff[3] + bd_ + 32]; \
  _Pragma("unroll") \
  for (int mf=0; mf<4; ++mf) a1[mf] = *(const short8*)&Ab[abase_r + mf*1024 + koff1]; \
  __builtin_amdgcn_s_barrier(); \
  asm volatile("s_waitcnt lgkmcnt(0)" ::: "memory"); \
  __builtin_amdgcn_sched_barrier(0); \
  __builtin_amdgcn_s_setprio(1); \
  _Pragma("unroll") \
  for (int mf=0; mf<4; ++mf) \
    _Pragma("unroll") \
    for (int nf=0; nf<2; ++nf) \
      acc[mf][nf] = __builtin_amdgcn_mfma_f32_16x16x32_bf16(a1[mf], b2v[nf], acc[mf][nf], 0,0,0); \
  __builtin_amdgcn_s_setprio(0); \
  __builtin_amdgcn_s_barrier(); \
  __builtin_amdgcn_sched_barrier(0); \
  /* ---- P3: MFMA a1 x b3 ---- */ \
  __builtin_amdgcn_s_barrier(); \
  __builtin_amdgcn_sched_barrier(0); \
  __builtin_amdgcn_s_setprio(1); \
  _Pragma("unroll") \
  for (int mf=0; mf<4; ++mf) \
    _Pragma("unroll") \
    for (int nf=0; nf<2; ++nf) \
      acc[mf][nf+2] = __builtin_amdgcn_mfma_f32_16x16x32_bf16(a1[mf], b3[nf], acc[mf][nf+2], 0,0,0); \
  __builtin_amdgcn_s_setprio(0); \
}

__global__ __launch_bounds__(256, 3) void conv1(const ushort_t* __restrict__ xpad,
                                                const ushort_t* __restrict__ w1t,
                                                const float* __restrict__ b1,
                                                ushort_t* __restrict__ hpad){
  __shared__ __align__(16) ushort_t Alds[2*8192];   // 2 bufs x 128 rows x 64 (32 KB)
  int orig = blockIdx.x;
  int bid = (orig & 7) * 288 + (orig >> 3);          // XCD swizzle, 2304 % 8 == 0
  int mt = bid & 1;
  int nt = bid >> 1;
  int b = nt / 72; int rem = nt - b*72;
  int y0 = (rem/3)*4, x0 = (rem - (rem/3)*3)*32;     // 4y x 32x pixel tile
  int o0 = mt*128;
  int t = threadIdx.x;
  int lane = t & 63, wave = t >> 6;
  int wm = wave & 1, wn = wave >> 1;                 // 2M x 2N waves (wave tile 64x64)
  int r = lane & 15, q = lane >> 4;

  // A staging maps (granule u = j*256 + t; row = (t>>3)+32j; stored oct u&7
  // holds logical oct (u&7)^(row&7) -> source pre-swizzled, dest linear)
  const int arow0 = t >> 3;                          // 0..31 (j adds 32 each)
  const int soct  = (t & 7) ^ (arow0 & 7);           // row&7 invariant in j
  const int adst  = t * 8;                           // + j*2048 + buf*8192
  const int asrc  = (o0 + arow0) * 1152 + soct * 8;  // + j*36864 + kt*64

  // A fragment read offsets (ushort units); row&7 == r&7 for all frag rows
  const int koff0 = ((0*4 + q) ^ (r & 7)) * 8;
  const int koff1 = ((1*4 + q) ^ (r & 7)) * 8;
  const int abase_r = (wm*64 + r) * 64;              // + mf*1024 (mf 0..3)

  // B global per-lane bases: pixel n = wn*64 + nf*16 + r
  int bgoff[4];
  #pragma unroll
  for (int nf=0; nf<4; ++nf){
    int n = wn*64 + nf*16 + r;
    int ty = n >> 5, tx = n & 31;
    bgoff[nf] = ((b*HP + y0+ty)*HP + (x0+tx))*CIN + q*8;
  }

  floatx4 acc[4][4];
  #pragma unroll
  for (int i=0;i<4;i++)
    #pragma unroll
    for (int j=0;j<4;j++) acc[i][j] = (floatx4){0.f,0.f,0.f,0.f};

  // prologue: stage A(0) -> buf0
  #pragma unroll
  for (int j=0;j<4;++j) async_ld16(&Alds[j*2048 + adst], &w1t[asrc + j*36864]);

  for (int kt=0; kt<17; ++kt){
    C1_TILE(kt, 1)
  }
  C1_TILE(17, 0)

  // epilogue: +bias, ReLU, bf16, store padded NHWC h
  #pragma unroll
  for (int mf=0; mf<4; ++mf){
    int o = o0 + wm*64 + mf*16 + q*4;
    float bias0 = b1[o], bias1 = b1[o+1], bias2 = b1[o+2], bias3 = b1[o+3];
    #pragma unroll
    for (int nf=0; nf<4; ++nf){
      int n = wn*64 + nf*16 + r;
      int ty = n >> 5, tx = n & 31;
      ushortx4 v;
      v[0] = f2bf(fmaxf(acc[mf][nf][0] + bias0, 0.f));
      v[1] = f2bf(fmaxf(acc[mf][nf][1] + bias1, 0.f));
      v[2] = f2bf(fmaxf(acc[mf][nf][2] + bias2, 0.f));
      v[3] = f2bf(fmaxf(acc[mf][nf][3] + bias3, 0.f));
      *(ushortx4*)&hpad[((b*HP + y0+ty+1)*HP + (x0+tx+1))*CH + o] = v;
    }
  }
}

// conv2: LDS-staged direct 3x3. Block = 8x8 output tile, halo 10x10 cells x 512B
// staged into LDS (51.2 KB) via global_load_lds: LDS dest linear, global SOURCE
// pre-swizzled chunk ^ (cell&7); reads apply the same XOR (both-sides involution).
// Wave = channel quarter (w addresses wave-uniform -> scalar cache); lane = pixel.
__global__ __launch_bounds__(256) void conv2(const ushort_t* __restrict__ hpad,
                                             const float* __restrict__ w2t,
                                             const float* __restrict__ b2,
                                             float* __restrict__ out){
  __shared__ __align__(16) ushort_t hlds[25600];   // 100 cells * 256 ushorts
  __shared__ float part[4][64][2];
  int bid = blockIdx.x;              // 2304 = 16 b * 12 yt * 12 xt
  int b = bid / 144; int rem = bid - b*144;
  int yt = rem / 12, xt = rem - yt*12;
  int y0 = yt*8, x0 = xt*8;          // padded window base = (y0, x0)
  int t = threadIdx.x;
  int wave = t >> 6, lane = t & 63;

  // stage 3200 x 16B chunks, pre-swizzled source
  for (int pass=0; pass<13; ++pass){
    int u = pass*256 + t;
    if (u < 3200){
      int cell = u >> 5, cf = u & 31;
      int hy = cell / 10, hx = cell - hy*10;
      const ushort_t* src = hpad + ((b*HP + y0+hy)*HP + (x0+hx))*CH
                                 + ((cf ^ (cell & 7)) << 3);
      async_ld16(&hlds[(pass*256 + wave*64)*8], src);
    }
  }
  __syncthreads();

  int q = __builtin_amdgcn_readfirstlane(wave);    // channel quarter, provably uniform
  int ty = lane >> 3, tx = lane & 7;
  float a0 = 0.f, a1 = 0.f;
  for (int tap=0; tap<9; ++tap){
    int dy = tap/3, dxx = tap - dy*3;
    int cell = (ty+dy)*10 + (tx+dxx);
    int s = cell & 7;
    const float* wp = w2t + (tap*256 + q*64)*2;    // scalar pointer
    #pragma unroll
    for (int g=0; g<8; ++g){
      int j = q*8 + g;
      ushortx8 hv = *(const ushortx8*)&hlds[cell*256 + ((j ^ s) << 3)];
      #pragma unroll
      for (int i=0;i<8;i++){
        float hf = bf2f(hv[i]);
        a0 = fmaf(hf, wp[(g*8+i)*2    ], a0);
        a1 = fmaf(hf, wp[(g*8+i)*2 + 1], a1);
      }
    }
  }
  part[wave][lane][0] = a0;
  part[wave][lane][1] = a1;
  __syncthreads();
  if (t < 128){
    int sel = t >> 6, pix = t & 63;
    float v = part[0][pix][sel] + part[1][pix][sel]
            + part[2][pix][sel] + part[3][pix][sel] + b2[sel];
    int yy = y0 + (pix >> 3), xx = x0 + (pix & 7);
    out[(b*2 + sel)*9216 + yy*96 + xx] = v;
  }
}

extern "C" void kernel_launch(void* const* d_in, const int* in_sizes, int n_in,
                              void* d_out, int out_size, void* d_ws, size_t ws_size,
                              hipStream_t stream){
  const float* x  = (const float*)d_in[0];
  const float* w1 = (const float*)d_in[1];
  const float* b1 = (const float*)d_in[2];
  const float* w2 = (const float*)d_in[3];
  const float* b2 = (const float*)d_in[4];
  float* out = (float*)d_out;
  char* ws = (char*)d_ws;
  ushort_t* xpad = (ushort_t*)(ws + XPAD_OFF);
  ushort_t* hpad = (ushort_t*)(ws + HPAD_OFF);
  ushort_t* w1t  = (ushort_t*)(ws + W1T_OFF);
  float*    w2t  = (float*)(ws + W2T_OFF);

  hipLaunchKernelGGL(prep_all, dim3(6978), dim3(256), 0, stream,
                     x, w1, w2, (uint32_t*)xpad, (uint32_t*)hpad, w1t, w2t, xpad);
  hipLaunchKernelGGL(conv1, dim3(2304), dim3(256), 0, stream, xpad, w1t, b1, hpad);
  hipLaunchKernelGGL(conv2, dim3(2304), dim3(256), 0, stream, hpad, w2t, b2, out);
}

// Round 17
// 156.166 us; speedup vs baseline: 1.5451x; 1.5451x over previous
//
#include <hip/hip_runtime.h>
#include <stdint.h>

typedef unsigned short ushort_t;
typedef __attribute__((ext_vector_type(8))) short short8;
typedef __attribute__((ext_vector_type(4))) float floatx4;
typedef __attribute__((ext_vector_type(4))) unsigned short ushortx4;
typedef __attribute__((ext_vector_type(8))) unsigned short ushortx8;

#define B_   16
#define CIN  128
#define CH   256
#define HW   96
#define HP   98

// ws layout (bytes)
#define XPAD_ELEMS (B_*HP*HP*CIN)            // bf16 elems
#define HPAD_ELEMS (B_*HP*HP*CH)             // bf16 elems
#define XPAD_OFF 0
#define HPAD_OFF (XPAD_ELEMS*2)
#define W1T_OFF  (HPAD_OFF + HPAD_ELEMS*2)
#define W2T_OFF  (W1T_OFF + 256*1152*2)

__device__ __forceinline__ ushort_t f2bf(float f){
  uint32_t u = __float_as_uint(f);
  u += 0x7FFF + ((u >> 16) & 1);   // RNE
  return (ushort_t)(u >> 16);
}
__device__ __forceinline__ float bf2f(ushort_t h){
  return __uint_as_float(((uint32_t)h) << 16);
}
__device__ __forceinline__ void async_ld16(void* lds, const void* g){
  __builtin_amdgcn_global_load_lds(
      (const __attribute__((address_space(1))) void*)g,
      (__attribute__((address_space(3))) void*)lds, 16, 0, 0);
}

// Zero one border word of a padded NHWC tensor. C2 = channels/2 (u32 words/cell).
__device__ __forceinline__ void zb(uint32_t* base, int C2, int tid){
  int perimg = 388*C2;
  int b = tid / perimg; int r = tid % perimg;
  int cell = r / C2;    int cu = r % C2;
  int y, x;
  if      (cell < 98)  { y = 0;            x = cell;       }
  else if (cell < 196) { y = 97;           x = cell - 98;  }
  else if (cell < 292) { y = cell - 195;   x = 0;          }
  else                 { y = cell - 291;   x = 97;         }
  base[((b*HP + y)*HP + x)*C2 + cu] = 0u;
}

// Fused prep: blocks [0,1152) = transform_x (NCHW fp32 -> padded NHWC bf16,
// 4 y-rows per block, full 256B-line stores); blocks [1152,6978) = border
// zeroing + w transforms.
__global__ __launch_bounds__(256) void prep_all(const float* __restrict__ x,
                                                const float* __restrict__ w1,
                                                const float* __restrict__ w2,
                                                uint32_t* __restrict__ xpadw,
                                                uint32_t* __restrict__ hpadw,
                                                ushort_t* __restrict__ w1t,
                                                float* __restrict__ w2t,
                                                ushort_t* __restrict__ xpad){
  __shared__ float lds[128][33];
  int bidx = blockIdx.x;
  int t = threadIdx.x;
  if (bidx < 1152){
    int xt = bidx % 3; int yt = (bidx/3) % 24; int b = bidx/72;
    int x0 = xt*32, y0 = yt*4;
    for (int yy=0; yy<4; ++yy){
      int y = y0 + yy;
      #pragma unroll
      for (int rep=0; rep<16; ++rep){
        int idx = rep*256 + t;
        int ci = idx >> 5, xj = idx & 31;
        lds[ci][xj] = x[((b*CIN + ci)*HW + y)*HW + x0 + xj];
      }
      __syncthreads();
      int px = t & 31, oc = t >> 5;      // oc = 16-channel group (0..7)
      ushort_t* dst = &xpad[((b*HP + y+1)*HP + x0+px+1)*CIN + oc*16];
      ushortx8 v0, v1;
      #pragma unroll
      for (int k=0;k<8;k++) v0[k] = f2bf(lds[oc*16+k][px]);
      #pragma unroll
      for (int k=0;k<8;k++) v1[k] = f2bf(lds[oc*16+8+k][px]);
      *(ushortx8*)dst = v0;
      *(ushortx8*)(dst+8) = v1;
      __syncthreads();
    }
  } else {
    int tid = (bidx - 1152)*256 + t;
    const int NZX = B_*388*64;
    const int NZH = B_*388*128;
    const int NW1 = 256*1152;
    if (tid < NZX){
      zb(xpadw, 64, tid);
    } else if (tid < NZX + NZH){
      zb(hpadw, 128, tid - NZX);
    } else if (tid < NZX + NZH + NW1){
      int r = tid - (NZX + NZH);
      int o = r / 1152, k = r - o*1152;
      int tap = k >> 7, c = k & 127;
      w1t[r] = f2bf(w1[(o*CIN + c)*9 + tap]);
    } else {
      int r = tid - (NZX + NZH + NW1);   // < 4608
      int ch = r & 1, c = (r >> 1) & 255, tap = r >> 9;
      w2t[r] = w2[(ch*CH + c)*9 + tap];
    }
  }
}

// ---------------------------------------------------------------------------
// conv1 v5 (session best, verbatim): BM=256, BN=192 (6y x 32x), BK=64, 18
// K-tiles, 512 thr / 8 waves 4Mx2N (wave tile 64x96, acc[4][6]), A 2-buf /
// B 3-buf, T2 both-sides swizzle, vmcnt(3) per-tile ledger (never drains
// until peeled kt=17), 4-phase/8-barrier schedule with forced lgkmcnt(0)
// per phase, T5 setprio, XCD swizzle, grid 768 = 3 clean CU rounds.
// Session plateau: ~106 us = 822 TF = 33% dense peak (= MfmaUtil), the
// 2-operand-LDS structure ceiling for this geometry. Per-element
// accumulation order fixed -> absmax must stay exactly 0.015625.
// ---------------------------------------------------------------------------
#define C1_TILE(KT, VMN, SA, SB) { \
  asm volatile("s_waitcnt vmcnt(" #VMN ")" ::: "memory"); \
  __builtin_amdgcn_s_barrier(); \
  __builtin_amdgcn_sched_barrier(0); \
  const int kt_ = (KT); \
  const ushort_t* Ab = &Alds[(kt_ & 1) * 16384]; \
  const ushort_t* Bb = &Blds[(kt_ % 3) * 12288]; \
  short8 aa0[4], cc0[4], bb0[3], bb1[3], dd0[3], dd1[3]; \
  /* ---- P0: A[0..3]@k0 + B[0..2]@k0 ; stage A(kt+1) j0,j1 ---- */ \
  _Pragma("unroll") \
  for (int nf=0; nf<3; ++nf) bb0[nf] = *(const short8*)&Bb[bbase_r + nf*1024 + koff0]; \
  _Pragma("unroll") \
  for (int mf=0; mf<4; ++mf) aa0[mf] = *(const short8*)&Ab[abase_r + mf*1024 + koff0]; \
  if (SA) { \
    const int ka_ = kt_ + 1; const int ab_ = (ka_ & 1) * 16384; \
    async_ld16(&Alds[ab_ +     0 + adst], &w1t[asrc +       0 + ka_*64]); \
    async_ld16(&Alds[ab_ +  4096 + adst], &w1t[asrc +   73728 + ka_*64]); \
  } \
  __builtin_amdgcn_s_barrier(); \
  asm volatile("s_waitcnt lgkmcnt(0)" ::: "memory"); \
  __builtin_amdgcn_sched_barrier(0); \
  __builtin_amdgcn_s_setprio(1); \
  _Pragma("unroll") \
  for (int mf=0; mf<4; ++mf) \
    _Pragma("unroll") \
    for (int nf=0; nf<3; ++nf) \
      acc[mf][nf] = __builtin_amdgcn_mfma_f32_16x16x32_bf16(aa0[mf], bb0[nf], acc[mf][nf], 0,0,0); \
  __builtin_amdgcn_s_setprio(0); \
  __builtin_amdgcn_s_barrier(); \
  __builtin_amdgcn_sched_barrier(0); \
  /* ---- P1: B[3..5]@k0 ; stage A(kt+1) j2,j3 ---- */ \
  _Pragma("unroll") \
  for (int nf=0; nf<3; ++nf) bb1[nf] = *(const short8*)&Bb[bbase_r + (nf+3)*1024 + koff0]; \
  if (SA) { \
    const int ka_ = kt_ + 1; const int ab_ = (ka_ & 1) * 16384; \
    async_ld16(&Alds[ab_ +  8192 + adst], &w1t[asrc + 2*73728 + ka_*64]); \
    async_ld16(&Alds[ab_ + 12288 + adst], &w1t[asrc + 3*73728 + ka_*64]); \
  } \
  __builtin_amdgcn_s_barrier(); \
  asm volatile("s_waitcnt lgkmcnt(0)" ::: "memory"); \
  __builtin_amdgcn_sched_barrier(0); \
  __builtin_amdgcn_s_setprio(1); \
  _Pragma("unroll") \
  for (int mf=0; mf<4; ++mf) \
    _Pragma("unroll") \
    for (int nf=0; nf<3; ++nf) \
      acc[mf][nf+3] = __builtin_amdgcn_mfma_f32_16x16x32_bf16(aa0[mf], bb1[nf], acc[mf][nf+3], 0,0,0); \
  __builtin_amdgcn_s_setprio(0); \
  __builtin_amdgcn_s_barrier(); \
  __builtin_amdgcn_sched_barrier(0); \
  /* ---- P2: A[0..3]@k1 + B[0..2]@k1 ; stage B(kt+2) j0,j1 ---- */ \
  _Pragma("unroll") \
  for (int nf=0; nf<3; ++nf) dd0[nf] = *(const short8*)&Bb[bbase_r + nf*1024 + koff1]; \
  _Pragma("unroll") \
  for (int mf=0; mf<4; ++mf) cc0[mf] = *(const short8*)&Ab[abase_r + mf*1024 + koff1]; \
  if (SB) { \
    const int kb_ = kt_ + 2; \
    const int tapb_ = kb_ >> 1; \
    const int dyb_ = tapb_/3; const int dxb_ = tapb_ - dyb_*3; \
    const int bdb_ = (dyb_*HP + dxb_)*CIN + (kb_&1)*64; \
    const int bb_ = (kb_ % 3) * 12288; \
    async_ld16(&Blds[bb_ +    0 + bdst], &xpad[bsrc +            bdb_]); \
    async_ld16(&Blds[bb_ + 4096 + bdst], &xpad[bsrc + 2*HP*CIN + bdb_]); \
  } \
  __builtin_amdgcn_s_barrier(); \
  asm volatile("s_waitcnt lgkmcnt(0)" ::: "memory"); \
  __builtin_amdgcn_sched_barrier(0); \
  __builtin_amdgcn_s_setprio(1); \
  _Pragma("unroll") \
  for (int mf=0; mf<4; ++mf) \
    _Pragma("unroll") \
    for (int nf=0; nf<3; ++nf) \
      acc[mf][nf] = __builtin_amdgcn_mfma_f32_16x16x32_bf16(cc0[mf], dd0[nf], acc[mf][nf], 0,0,0); \
  __builtin_amdgcn_s_setprio(0); \
  __builtin_amdgcn_s_barrier(); \
  __builtin_amdgcn_sched_barrier(0); \
  /* ---- P3: B[3..5]@k1 ; stage B(kt+2) j2 ---- */ \
  _Pragma("unroll") \
  for (int nf=0; nf<3; ++nf) dd1[nf] = *(const short8*)&Bb[bbase_r + (nf+3)*1024 + koff1]; \
  if (SB) { \
    const int kb_ = kt_ + 2; \
    const int tapb_ = kb_ >> 1; \
    const int dyb_ = tapb_/3; const int dxb_ = tapb_ - dyb_*3; \
    const int bdb_ = (dyb_*HP + dxb_)*CIN + (kb_&1)*64; \
    const int bb_ = (kb_ % 3) * 12288; \
    async_ld16(&Blds[bb_ + 8192 + bdst], &xpad[bsrc + 4*HP*CIN + bdb_]); \
  } \
  __builtin_amdgcn_s_barrier(); \
  asm volatile("s_waitcnt lgkmcnt(0)" ::: "memory"); \
  __builtin_amdgcn_sched_barrier(0); \
  __builtin_amdgcn_s_setprio(1); \
  _Pragma("unroll") \
  for (int mf=0; mf<4; ++mf) \
    _Pragma("unroll") \
    for (int nf=0; nf<3; ++nf) \
      acc[mf][nf+3] = __builtin_amdgcn_mfma_f32_16x16x32_bf16(cc0[mf], dd1[nf], acc[mf][nf+3], 0,0,0); \
  __builtin_amdgcn_s_setprio(0); \
}

__global__ __launch_bounds__(512, 1) void conv1(const ushort_t* __restrict__ xpad,
                                                const ushort_t* __restrict__ w1t,
                                                const float* __restrict__ b1,
                                                ushort_t* __restrict__ hpad){
  __shared__ __align__(16) ushort_t Alds[2*16384];   // 2 bufs x 256 rows x 64 (64 KB)
  __shared__ __align__(16) ushort_t Blds[3*12288];   // 3 bufs x 192 rows x 64 (72 KB)
  int orig = blockIdx.x;
  int bid = (orig & 7) * 96 + (orig >> 3);           // XCD swizzle, 768 % 8 == 0
  int b = bid / 48; int rem = bid - b*48;
  int y0 = (rem/3)*6, x0 = (rem - (rem/3)*3)*32;     // 6y x 32x pixel tile
  int t = threadIdx.x;
  int lane = t & 63, wave = t >> 6;
  int wm = wave & 3, wn = wave >> 2;                 // 4M x 2N waves (wave tile 64x96)
  int r = lane & 15, q = lane >> 4;

  // staging maps (granule v = j*512 + t; row = v>>3; stored oct = v&7 holds
  // logical oct (v&7)^(row&7) -> source pre-swizzled, LDS dest linear)
  const int arow0 = t >> 3;                          // 0..63 (j adds 64 each)
  const int soct  = (t & 7) ^ (arow0 & 7);           // same for all j (64%8==0)
  const int adst  = t * 8;                           // + j*4096 + buf*16384
  const int asrc  = arow0 * 1152 + soct * 8;         // + j*73728 + kt*64
  const int bty0  = arow0 >> 5, btx0 = arow0 & 31;   // B row = pixel index
  const int bdst  = t * 8;                           // + j*4096 + buf*12288
  const int bsrc  = ((b*HP + y0 + bty0)*HP + x0 + btx0)*CIN + soct * 8; // + j*2*HP*CIN + bd

  // fragment read offsets (ushort units); row&7 == r&7 for all frag rows
  const int koff0 = ((0*4 + q) ^ (r & 7)) * 8;
  const int koff1 = ((1*4 + q) ^ (r & 7)) * 8;
  const int abase_r = (wm*64 + r) * 64;              // + mf*1024 (mf 0..3)
  const int bbase_r = (wn*96 + r) * 64;              // + nf*1024 (nf 0..5)

  floatx4 acc[4][6];
  #pragma unroll
  for (int i=0;i<4;i++)
    #pragma unroll
    for (int j=0;j<6;j++) acc[i][j] = (floatx4){0.f,0.f,0.f,0.f};

  // prologue: ledger order B-for-0(3), A-for-0(4), B-for-1(3)
  #pragma unroll
  for (int j=0;j<3;++j) async_ld16(&Blds[0     + j*4096 + bdst], &xpad[bsrc + j*(2*HP*CIN)]);
  #pragma unroll
  for (int j=0;j<4;++j) async_ld16(&Alds[0     + j*4096 + adst], &w1t[asrc + j*73728]);
  #pragma unroll
  for (int j=0;j<3;++j) async_ld16(&Blds[12288 + j*4096 + bdst], &xpad[bsrc + j*(2*HP*CIN) + 64]);

  for (int kt=0; kt<16; ++kt){
    C1_TILE(kt, 3, 1, 1)
  }
  C1_TILE(16, 3, 1, 0)
  C1_TILE(17, 0, 0, 0)

  // epilogue: +bias, ReLU, bf16, store padded NHWC h
  #pragma unroll
  for (int mf=0; mf<4; ++mf){
    int o = wm*64 + mf*16 + q*4;
    float bias0 = b1[o], bias1 = b1[o+1], bias2 = b1[o+2], bias3 = b1[o+3];
    #pragma unroll
    for (int nf=0; nf<6; ++nf){
      int n = wn*96 + nf*16 + r;
      int ty = n >> 5, tx = n & 31;
      ushortx4 v;
      v[0] = f2bf(fmaxf(acc[mf][nf][0] + bias0, 0.f));
      v[1] = f2bf(fmaxf(acc[mf][nf][1] + bias1, 0.f));
      v[2] = f2bf(fmaxf(acc[mf][nf][2] + bias2, 0.f));
      v[3] = f2bf(fmaxf(acc[mf][nf][3] + bias3, 0.f));
      *(ushortx4*)&hpad[((b*HP + y0+ty+1)*HP + (x0+tx+1))*CH + o] = v;
    }
  }
}

// conv2: LDS-staged direct 3x3. Block = 8x8 output tile, halo 10x10 cells x 512B
// staged into LDS (51.2 KB) via global_load_lds: LDS dest linear, global SOURCE
// pre-swizzled chunk ^ (cell&7); reads apply the same XOR (both-sides involution).
// Wave = channel quarter (w addresses wave-uniform -> scalar cache); lane = pixel.
__global__ __launch_bounds__(256) void conv2(const ushort_t* __restrict__ hpad,
                                             const float* __restrict__ w2t,
                                             const float* __restrict__ b2,
                                             float* __restrict__ out){
  __shared__ __align__(16) ushort_t hlds[25600];   // 100 cells * 256 ushorts
  __shared__ float part[4][64][2];
  int bid = blockIdx.x;              // 2304 = 16 b * 12 yt * 12 xt
  int b = bid / 144; int rem = bid - b*144;
  int yt = rem / 12, xt = rem - yt*12;
  int y0 = yt*8, x0 = xt*8;          // padded window base = (y0, x0)
  int t = threadIdx.x;
  int wave = t >> 6, lane = t & 63;

  // stage 3200 x 16B chunks, pre-swizzled source
  for (int pass=0; pass<13; ++pass){
    int u = pass*256 + t;
    if (u < 3200){
      int cell = u >> 5, cf = u & 31;
      int hy = cell / 10, hx = cell - hy*10;
      const ushort_t* src = hpad + ((b*HP + y0+hy)*HP + (x0+hx))*CH
                                 + ((cf ^ (cell & 7)) << 3);
      async_ld16(&hlds[(pass*256 + wave*64)*8], src);
    }
  }
  __syncthreads();

  int q = __builtin_amdgcn_readfirstlane(wave);    // channel quarter, provably uniform
  int ty = lane >> 3, tx = lane & 7;
  float a0 = 0.f, a1 = 0.f;
  for (int tap=0; tap<9; ++tap){
    int dy = tap/3, dxx = tap - dy*3;
    int cell = (ty+dy)*10 + (tx+dxx);
    int s = cell & 7;
    const float* wp = w2t + (tap*256 + q*64)*2;    // scalar pointer
    #pragma unroll
    for (int g=0; g<8; ++g){
      int j = q*8 + g;
      ushortx8 hv = *(const ushortx8*)&hlds[cell*256 + ((j ^ s) << 3)];
      #pragma unroll
      for (int i=0;i<8;i++){
        float hf = bf2f(hv[i]);
        a0 = fmaf(hf, wp[(g*8+i)*2    ], a0);
        a1 = fmaf(hf, wp[(g*8+i)*2 + 1], a1);
      }
    }
  }
  part[wave][lane][0] = a0;
  part[wave][lane][1] = a1;
  __syncthreads();
  if (t < 128){
    int sel = t >> 6, pix = t & 63;
    float v = part[0][pix][sel] + part[1][pix][sel]
            + part[2][pix][sel] + part[3][pix][sel] + b2[sel];
    int yy = y0 + (pix >> 3), xx = x0 + (pix & 7);
    out[(b*2 + sel)*9216 + yy*96 + xx] = v;
  }
}

extern "C" void kernel_launch(void* const* d_in, const int* in_sizes, int n_in,
                              void* d_out, int out_size, void* d_ws, size_t ws_size,
                              hipStream_t stream){
  const float* x  = (const float*)d_in[0];
  const float* w1 = (const float*)d_in[1];
  const float* b1 = (const float*)d_in[2];
  const float* w2 = (const float*)d_in[3];
  const float* b2 = (const float*)d_in[4];
  float* out = (float*)d_out;
  char* ws = (char*)d_ws;
  ushort_t* xpad = (ushort_t*)(ws + XPAD_OFF);
  ushort_t* hpad = (ushort_t*)(ws + HPAD_OFF);
  ushort_t* w1t  = (ushort_t*)(ws + W1T_OFF);
  float*    w2t  = (float*)(ws + W2T_OFF);

  hipLaunchKernelGGL(prep_all, dim3(6978), dim3(256), 0, stream,
                     x, w1, w2, (uint32_t*)xpad, (uint32_t*)hpad, w1t, w2t, xpad);
  hipLaunchKernelGGL(conv1, dim3(768),  dim3(512), 0, stream, xpad, w1t, b1, hpad);
  hipLaunchKernelGGL(conv2, dim3(2304), dim3(256), 0, stream, hpad, w2t, b2, out);
}